// Round 1
// baseline (576.087 us; speedup 1.0000x reference)
//
#include <hip/hip_runtime.h>

// Problem constants
#define TT 4096      // tokens (B*L)
#define DD 1024      // model dim
#define HH 2048      // hidden dim
#define EE 8         // experts
#define TK 8192      // T*K pairs (K=2)

typedef short  bf16x8 __attribute__((ext_vector_type(8)));
typedef float  f32x4  __attribute__((ext_vector_type(4)));

__device__ __forceinline__ unsigned short f2b(float f) {
    unsigned int u = __float_as_uint(f);
    unsigned int r = (u + 0x7fffu + ((u >> 16) & 1u)) >> 16;  // RNE
    return (unsigned short)r;
}
__device__ __forceinline__ float b2f(unsigned short b) {
    return __uint_as_float(((unsigned int)b) << 16);
}

#define GLOAD_LDS16(SRC, DST) __builtin_amdgcn_global_load_lds( \
    (const __attribute__((address_space(1))) unsigned int*)(SRC), \
    (__attribute__((address_space(3))) unsigned int*)(DST), 16, 0, 0)

// ---------------- x -> bf16 ----------------
__global__ void convert_x(const float* __restrict__ x, unsigned short* __restrict__ xb) {
    int i = blockIdx.x * blockDim.x + threadIdx.x;      // 0 .. T*D/8-1
    const float4* src = (const float4*)x + (size_t)i * 2;
    float4 a = src[0], b = src[1];
    union { unsigned short us[8]; uint4 v; } o;
    o.us[0] = f2b(a.x); o.us[1] = f2b(a.y); o.us[2] = f2b(a.z); o.us[3] = f2b(a.w);
    o.us[4] = f2b(b.x); o.us[5] = f2b(b.y); o.us[6] = f2b(b.z); o.us[7] = f2b(b.w);
    ((uint4*)xb)[i] = o.v;
}

// ------------- weight transpose + bf16 convert: src [E][Kd][Nd] -> dst [E][Nd][Kd] -------------
__global__ void conv_transpose(const float* __restrict__ src, unsigned short* __restrict__ dst,
                               int Kd, int Nd) {
    int e  = blockIdx.z;
    int n0 = blockIdx.x * 64;
    int k0 = blockIdx.y * 64;
    const float* s = src + (size_t)e * Kd * Nd;
    unsigned short* d = dst + (size_t)e * Kd * Nd;
    __shared__ float tile[64][65];
    int c  = threadIdx.x & 63;
    int r4 = threadIdx.x >> 6;
#pragma unroll
    for (int i = 0; i < 16; i++) {
        int r = r4 + i * 4;
        tile[r][c] = s[(size_t)(k0 + r) * Nd + n0 + c];
    }
    __syncthreads();
#pragma unroll
    for (int i = 0; i < 16; i++) {
        int r = r4 + i * 4;
        d[(size_t)(n0 + r) * Kd + k0 + c] = f2b(tile[c][r]);
    }
}

// ---------------- stats zero ----------------
__global__ void zero_stats(int* p) {
    if (threadIdx.x < 128) p[threadIdx.x] = 0;
}

// ---------------- gating ----------------
// stats_f: [0..7]=psum, [8..15]=gsum, [16]=zl_sum
// stats_i: [0..7]=cnt_route, [8..15]=cnt_pos, [16..23]=cursor, [24..32]=offs
__global__ void gating(const float* __restrict__ x, const float* __restrict__ wg,
                       const float* __restrict__ eps,
                       float* __restrict__ stats_f, int* __restrict__ stats_i,
                       int* __restrict__ top_i, float* __restrict__ top_g) {
    __shared__ float l_psum[8], l_gsum[8], l_zl;
    __shared__ int   l_cr[8], l_cp[8];
    int tid = threadIdx.x;
    if (tid < 8) { l_psum[tid] = 0.f; l_gsum[tid] = 0.f; l_cr[tid] = 0; l_cp[tid] = 0; }
    if (tid == 0) l_zl = 0.f;
    __syncthreads();
    int wave = tid >> 6, lane = tid & 63;
    for (int it = 0; it < 16; ++it) {
        int t = blockIdx.x * 64 + it * 4 + wave;
        const float* xr = x + (size_t)t * DD;
        float acc[16];
#pragma unroll
        for (int j = 0; j < 16; j++) acc[j] = 0.f;
        for (int i = 0; i < 16; i++) {
            int dd = lane + i * 64;
            float xv = xr[dd];
            const float4* wr = (const float4*)(wg + dd * 16);
            float4 w0 = wr[0], w1 = wr[1], w2 = wr[2], w3 = wr[3];
            acc[0]  += xv * w0.x; acc[1]  += xv * w0.y; acc[2]  += xv * w0.z; acc[3]  += xv * w0.w;
            acc[4]  += xv * w1.x; acc[5]  += xv * w1.y; acc[6]  += xv * w1.z; acc[7]  += xv * w1.w;
            acc[8]  += xv * w2.x; acc[9]  += xv * w2.y; acc[10] += xv * w2.z; acc[11] += xv * w2.w;
            acc[12] += xv * w3.x; acc[13] += xv * w3.y; acc[14] += xv * w3.z; acc[15] += xv * w3.w;
        }
#pragma unroll
        for (int j = 0; j < 16; j++)
            for (int o = 32; o > 0; o >>= 1) acc[j] += __shfl_xor(acc[j], o, 64);
        if (lane == 0) {
            float lg[8], p[8];
            float mx = -1e30f;
            for (int e2 = 0; e2 < 8; e2++) {
                float raw = acc[8 + e2];
                float sp = (raw > 20.f) ? raw : log1pf(__expf(raw));
                float l = acc[e2] + eps[(size_t)t * 8 + e2] * (sp + 0.01f);
                lg[e2] = l; mx = fmaxf(mx, l);
            }
            float se = 0.f;
            for (int e2 = 0; e2 < 8; e2++) { p[e2] = __expf(lg[e2] - mx); se += p[e2]; }
            float lse = mx + logf(se);
            float inv = 1.f / se;
            for (int e2 = 0; e2 < 8; e2++) p[e2] *= inv;
            int i0 = 0;
            for (int e2 = 1; e2 < 8; e2++) if (p[e2] > p[i0]) i0 = e2;
            int i1 = (i0 == 0) ? 1 : 0;
            for (int e2 = 0; e2 < 8; e2++) if (e2 != i0 && p[e2] > p[i1]) i1 = e2;
            float g0 = p[i0], g1 = p[i1];
            top_i[t * 2] = i0; top_i[t * 2 + 1] = i1;
            top_g[t * 2] = g0; top_g[t * 2 + 1] = g1;
            for (int e2 = 0; e2 < 8; e2++) atomicAdd(&l_psum[e2], p[e2]);
            atomicAdd(&l_gsum[i0], g0); atomicAdd(&l_gsum[i1], g1);
            atomicAdd(&l_zl, lse * lse);
            atomicAdd(&l_cr[i0], 1); atomicAdd(&l_cr[i1], 1);
            if (g0 > 0.f) atomicAdd(&l_cp[i0], 1);
            if (g1 > 0.f) atomicAdd(&l_cp[i1], 1);
        }
    }
    __syncthreads();
    if (tid < 8) {
        atomicAdd(&stats_f[tid],      l_psum[tid]);
        atomicAdd(&stats_f[8 + tid],  l_gsum[tid]);
        atomicAdd(&stats_i[tid],      l_cr[tid]);
        atomicAdd(&stats_i[8 + tid],  l_cp[tid]);
    }
    if (tid == 0) atomicAdd(&stats_f[16], l_zl);
}

// ---------------- offsets + loss ----------------
__global__ void offsets_loss(const float* __restrict__ stats_f, int* __restrict__ stats_i,
                             float* __restrict__ loss_out) {
    if (threadIdx.x != 0) return;
    int off = 0;
    for (int e = 0; e < 8; e++) { stats_i[24 + e] = off; off += stats_i[e]; }
    stats_i[32] = off;
    float gs = 0.f;
    for (int e = 0; e < 8; e++) gs += stats_f[8 + e];
    float var = 0.f;
    for (int e = 0; e < 8; e++) {
        float gn = stats_f[8 + e] / gs;
        float d = gn - 0.125f;
        var += d * d;
    }
    var /= 7.f;
    float cv = var / (0.015625f + 1e-10f);
    float ps = 0.f, cs = 0.f;
    for (int e = 0; e < 8; e++) { ps += stats_f[e]; cs += (float)stats_i[8 + e]; }
    float dot = 0.f;
    for (int e = 0; e < 8; e++) dot += (stats_f[e] / ps) * ((float)stats_i[8 + e] / cs);
    float sw = (1.f - dot) * 8.f;
    float zl = stats_f[16] / (float)TT;
    *loss_out = 0.01f * cv + 0.1f * sw + 0.0001f * zl;
}

// ---------------- scatter pairs ----------------
__global__ void scatter(const int* __restrict__ top_i, int* __restrict__ stats_i,
                        int* __restrict__ row_token, int* __restrict__ pair_pos) {
    __shared__ int lcnt[8], lbase[8];
    int tid = threadIdx.x;
    if (tid < 8) lcnt[tid] = 0;
    __syncthreads();
    int t = blockIdx.x * 256 + tid;
    int e0 = top_i[t * 2], e1 = top_i[t * 2 + 1];
    int p0 = atomicAdd(&lcnt[e0], 1);
    int p1 = atomicAdd(&lcnt[e1], 1);
    __syncthreads();
    if (tid < 8) lbase[tid] = atomicAdd(&stats_i[16 + tid], lcnt[tid]);
    __syncthreads();
    const int* offs = stats_i + 24;
    int idx0 = offs[e0] + lbase[e0] + p0;
    int idx1 = offs[e1] + lbase[e1] + p1;
    row_token[idx0] = t;
    row_token[idx1] = t;
    pair_pos[t * 2] = idx0;
    pair_pos[t * 2 + 1] = idx1;
}

// ---------------- grouped GEMM: C[rows, N] = A[rows, K] @ Bt[N, K]^T ----------------
// 128x128 tile, BK=64, 4 waves each computing a 64x64 quadrant via 16x16x32 bf16 MFMA.
template<int KDIM, bool GATHER, bool RELU>
__global__ __launch_bounds__(256) void gemm_tile(
    const unsigned short* __restrict__ A,
    const unsigned short* __restrict__ Bt,
    unsigned short* __restrict__ C, int ldc,
    const int* __restrict__ row_token, const int* __restrict__ stats_i) {
    const int* offs = stats_i + 24;
    int e  = blockIdx.z;
    int off = offs[e];
    int ne  = offs[e + 1] - off;
    int rt = blockIdx.x;
    if (rt * 128 >= ne) return;
    int n0 = blockIdx.y * 128;
    int NDIM = gridDim.y * 128;
    __shared__ __align__(16) unsigned short Al[128 * 64];
    __shared__ __align__(16) unsigned short Bl[128 * 64];
    __shared__ int toks[128];
    int tid = threadIdx.x;
    if (GATHER) {
        if (tid < 128) toks[tid] = row_token[min(off + rt * 128 + tid, TK - 1)];
    }
    __syncthreads();
    int lane = tid & 63, wave = tid >> 6;
    int wm = wave >> 1, wn = wave & 1;
    f32x4 acc[4][4];
#pragma unroll
    for (int m = 0; m < 4; m++)
#pragma unroll
        for (int n = 0; n < 4; n++)
#pragma unroll
            for (int i = 0; i < 4; i++) acc[m][n][i] = 0.f;
    const unsigned short* Bte = Bt + (size_t)e * NDIM * KDIM;
    for (int kb = 0; kb < KDIM / 64; ++kb) {
#pragma unroll
        for (int r = 0; r < 4; r++) {
            int glin = r * 256 + tid;
            int row = glin >> 3, sl = glin & 7, g = sl ^ (row & 7);
            const unsigned short* srcA;
            if (GATHER) {
                srcA = A + (size_t)toks[row] * KDIM + kb * 64 + g * 8;
            } else {
                int ar = min(off + rt * 128 + row, TK - 1);
                srcA = A + (size_t)ar * KDIM + kb * 64 + g * 8;
            }
            GLOAD_LDS16(srcA, Al + r * 2048 + wave * 512);
            const unsigned short* srcB = Bte + (size_t)(n0 + row) * KDIM + kb * 64 + g * 8;
            GLOAD_LDS16(srcB, Bl + r * 2048 + wave * 512);
        }
        __syncthreads();
#pragma unroll
        for (int kk = 0; kk < 2; kk++) {
            bf16x8 av[4], bv[4];
#pragma unroll
            for (int m = 0; m < 4; m++) {
                int row = wm * 64 + m * 16 + (lane & 15);
                int g = (kk * 4 + (lane >> 4)) ^ (row & 7);
                av[m] = *(const bf16x8*)(Al + row * 64 + g * 8);
            }
#pragma unroll
            for (int n = 0; n < 4; n++) {
                int row = wn * 64 + n * 16 + (lane & 15);
                int g = (kk * 4 + (lane >> 4)) ^ (row & 7);
                bv[n] = *(const bf16x8*)(Bl + row * 64 + g * 8);
            }
#pragma unroll
            for (int m = 0; m < 4; m++)
#pragma unroll
                for (int n = 0; n < 4; n++)
                    acc[m][n] = __builtin_amdgcn_mfma_f32_16x16x32_bf16(av[m], bv[n], acc[m][n], 0, 0, 0);
        }
        __syncthreads();
    }
#pragma unroll
    for (int m = 0; m < 4; m++) {
        int rr0 = rt * 128 + wm * 64 + m * 16 + (lane >> 4) * 4;
#pragma unroll
        for (int i = 0; i < 4; i++) {
            if (rr0 + i < ne) {
                size_t grow = (size_t)(off + rr0 + i);
#pragma unroll
                for (int n = 0; n < 4; n++) {
                    int col = n0 + wn * 64 + n * 16 + (lane & 15);
                    float v = acc[m][n][i];
                    if (RELU) v = fmaxf(v, 0.f);
                    C[grow * ldc + col] = f2b(v);
                }
            }
        }
    }
}

// ---------------- gated combine ----------------
__global__ void combine(const unsigned short* __restrict__ outp,
                        const int* __restrict__ pair_pos, const float* __restrict__ top_g,
                        float* __restrict__ y) {
    int t = blockIdx.x;
    int tid = threadIdx.x;
    int i0 = pair_pos[t * 2], i1 = pair_pos[t * 2 + 1];
    float g0 = top_g[t * 2], g1 = top_g[t * 2 + 1];
    int d0 = tid * 4;
    ushort4 a = *(const ushort4*)(outp + (size_t)i0 * DD + d0);
    ushort4 b = *(const ushort4*)(outp + (size_t)i1 * DD + d0);
    float4 o;
    o.x = g0 * b2f(a.x) + g1 * b2f(b.x);
    o.y = g0 * b2f(a.y) + g1 * b2f(b.y);
    o.z = g0 * b2f(a.z) + g1 * b2f(b.z);
    o.w = g0 * b2f(a.w) + g1 * b2f(b.w);
    *(float4*)(y + (size_t)t * DD + d0) = o;
}

extern "C" void kernel_launch(void* const* d_in, const int* in_sizes, int n_in,
                              void* d_out, int out_size, void* d_ws, size_t ws_size,
                              hipStream_t stream) {
    const float* x   = (const float*)d_in[0];
    const float* wg  = (const float*)d_in[1];
    const float* w1  = (const float*)d_in[2];
    const float* w2  = (const float*)d_in[3];
    const float* eps = (const float*)d_in[4];
    float* y = (float*)d_out;
    char* ws = (char*)d_ws;

    unsigned short* xb    = (unsigned short*)(ws);                 //  8 MB
    unsigned short* w1bT  = (unsigned short*)(ws + 8388608);       // 32 MB  [E][H][D]
    unsigned short* w2bT  = (unsigned short*)(ws + 41943040);      // 32 MB  [E][D][H]
    unsigned short* hbuf  = (unsigned short*)(ws + 75497472);      // 32 MB  [TK][H]
    unsigned short* outp  = (unsigned short*)(ws + 109051904);     // 16 MB  [TK][D]
    int*   top_i    = (int*)(ws + 125829120);
    float* top_g    = (float*)(ws + 125861888);
    int*   row_token= (int*)(ws + 125894656);
    int*   pair_pos = (int*)(ws + 125927424);
    float* stats_f  = (float*)(ws + 125960192);
    int*   stats_i  = (int*)(ws + 125960192 + 128);

    zero_stats<<<1, 128, 0, stream>>>((int*)(ws + 125960192));
    convert_x<<<2048, 256, 0, stream>>>(x, xb);
    conv_transpose<<<dim3(32, 16, 8), 256, 0, stream>>>(w1, w1bT, 1024, 2048);
    conv_transpose<<<dim3(16, 32, 8), 256, 0, stream>>>(w2, w2bT, 2048, 1024);
    gating<<<64, 256, 0, stream>>>(x, wg, eps, stats_f, stats_i, top_i, top_g);
    offsets_loss<<<1, 64, 0, stream>>>(stats_f, stats_i, y + (size_t)TT * DD);
    scatter<<<16, 256, 0, stream>>>(top_i, stats_i, row_token, pair_pos);
    gemm_tile<1024, true,  true ><<<dim3(32, 16, 8), 256, 0, stream>>>(xb,   w1bT, hbuf, HH, row_token, stats_i);
    gemm_tile<2048, false, false><<<dim3(32, 8, 8),  256, 0, stream>>>(hbuf, w2bT, outp, DD, row_token, stats_i);
    combine<<<4096, 256, 0, stream>>>(outp, pair_pos, top_g, y);
}

// Round 2
// 406.344 us; speedup vs baseline: 1.4177x; 1.4177x over previous
//
#include <hip/hip_runtime.h>

// Problem constants
#define TT 4096      // tokens (B*L)
#define DD 1024      // model dim
#define HH 2048      // hidden dim
#define EE 8         // experts
#define TK 8192      // T*K pairs (K=2)

typedef short  bf16x8 __attribute__((ext_vector_type(8)));
typedef float  f32x4  __attribute__((ext_vector_type(4)));

__device__ __forceinline__ unsigned short f2b(float f) {
    unsigned int u = __float_as_uint(f);
    unsigned int r = (u + 0x7fffu + ((u >> 16) & 1u)) >> 16;  // RNE
    return (unsigned short)r;
}
__device__ __forceinline__ float b2f(unsigned short b) {
    return __uint_as_float(((unsigned int)b) << 16);
}

#define GLOAD_LDS16(SRC, DST) __builtin_amdgcn_global_load_lds( \
    (const __attribute__((address_space(1))) unsigned int*)(SRC), \
    (__attribute__((address_space(3))) unsigned int*)(DST), 16, 0, 0)

// ------------- weight transpose + bf16 convert: src [E][Kd][Nd] -> dst [E][Nd][Kd] -------------
__global__ void conv_transpose(const float* __restrict__ src, unsigned short* __restrict__ dst,
                               int Kd, int Nd) {
    int e  = blockIdx.z;
    int n0 = blockIdx.x * 64;
    int k0 = blockIdx.y * 64;
    const float* s = src + (size_t)e * Kd * Nd;
    unsigned short* d = dst + (size_t)e * Kd * Nd;
    __shared__ float tile[64][65];
    int c  = threadIdx.x & 63;
    int r4 = threadIdx.x >> 6;
#pragma unroll
    for (int i = 0; i < 16; i++) {
        int r = r4 + i * 4;
        tile[r][c] = s[(size_t)(k0 + r) * Nd + n0 + c];
    }
    __syncthreads();
#pragma unroll
    for (int i = 0; i < 16; i++) {
        int r = r4 + i * 4;
        d[(size_t)(n0 + r) * Kd + k0 + c] = f2b(tile[c][r]);
    }
}

// ---------------- stats zero ----------------
__global__ void zero_stats(int* p) {
    if (threadIdx.x < 128) p[threadIdx.x] = 0;
}

// ---------------- gating (one token per wave) + fused x->bf16 convert ----------------
// stats_f: [0..7]=psum, [8..15]=gsum, [16]=zl_sum
// stats_i: [0..7]=cnt_route, [8..15]=cnt_pos, [16..23]=cursor, [24..32]=offs
__global__ __launch_bounds__(256) void gating(const float* __restrict__ x, const float* __restrict__ wg,
                       const float* __restrict__ eps,
                       float* __restrict__ stats_f, int* __restrict__ stats_i,
                       int* __restrict__ top_i, float* __restrict__ top_g,
                       unsigned short* __restrict__ xb) {
    __shared__ float l_psum[8], l_gsum[8], l_zl;
    __shared__ int   l_cr[8], l_cp[8];
    int tid = threadIdx.x;
    if (tid < 8) { l_psum[tid] = 0.f; l_gsum[tid] = 0.f; l_cr[tid] = 0; l_cp[tid] = 0; }
    if (tid == 0) l_zl = 0.f;
    __syncthreads();
    int wave = tid >> 6, lane = tid & 63;
    int t = blockIdx.x * 4 + wave;
    const float* xr = x + (size_t)t * DD;
    unsigned short* xbr = xb + (size_t)t * DD;
    float acc[16];
#pragma unroll
    for (int j = 0; j < 16; j++) acc[j] = 0.f;
#pragma unroll
    for (int i = 0; i < 16; i++) {
        int dd = lane + i * 64;
        float xv = xr[dd];
        xbr[dd] = f2b(xv);
        const float4* wr = (const float4*)(wg + dd * 16);
        float4 w0 = wr[0], w1 = wr[1], w2 = wr[2], w3 = wr[3];
        acc[0]  += xv * w0.x; acc[1]  += xv * w0.y; acc[2]  += xv * w0.z; acc[3]  += xv * w0.w;
        acc[4]  += xv * w1.x; acc[5]  += xv * w1.y; acc[6]  += xv * w1.z; acc[7]  += xv * w1.w;
        acc[8]  += xv * w2.x; acc[9]  += xv * w2.y; acc[10] += xv * w2.z; acc[11] += xv * w2.w;
        acc[12] += xv * w3.x; acc[13] += xv * w3.y; acc[14] += xv * w3.z; acc[15] += xv * w3.w;
    }
#pragma unroll
    for (int j = 0; j < 16; j++)
#pragma unroll
        for (int o = 32; o > 0; o >>= 1) acc[j] += __shfl_xor(acc[j], o, 64);
    if (lane == 0) {
        float lg[8], p[8];
        float mx = -1e30f;
        for (int e2 = 0; e2 < 8; e2++) {
            float raw = acc[8 + e2];
            float sp = (raw > 20.f) ? raw : log1pf(__expf(raw));
            float l = acc[e2] + eps[(size_t)t * 8 + e2] * (sp + 0.01f);
            lg[e2] = l; mx = fmaxf(mx, l);
        }
        float se = 0.f;
        for (int e2 = 0; e2 < 8; e2++) { p[e2] = __expf(lg[e2] - mx); se += p[e2]; }
        float lse = mx + logf(se);
        float inv = 1.f / se;
        for (int e2 = 0; e2 < 8; e2++) p[e2] *= inv;
        int i0 = 0;
        for (int e2 = 1; e2 < 8; e2++) if (p[e2] > p[i0]) i0 = e2;
        int i1 = (i0 == 0) ? 1 : 0;
        for (int e2 = 0; e2 < 8; e2++) if (e2 != i0 && p[e2] > p[i1]) i1 = e2;
        float g0 = p[i0], g1 = p[i1];
        top_i[t * 2] = i0; top_i[t * 2 + 1] = i1;
        top_g[t * 2] = g0; top_g[t * 2 + 1] = g1;
        for (int e2 = 0; e2 < 8; e2++) atomicAdd(&l_psum[e2], p[e2]);
        atomicAdd(&l_gsum[i0], g0); atomicAdd(&l_gsum[i1], g1);
        atomicAdd(&l_zl, lse * lse);
        atomicAdd(&l_cr[i0], 1); atomicAdd(&l_cr[i1], 1);
        if (g0 > 0.f) atomicAdd(&l_cp[i0], 1);
        if (g1 > 0.f) atomicAdd(&l_cp[i1], 1);
    }
    __syncthreads();
    if (tid < 8) {
        atomicAdd(&stats_f[tid],      l_psum[tid]);
        atomicAdd(&stats_f[8 + tid],  l_gsum[tid]);
        atomicAdd(&stats_i[tid],      l_cr[tid]);
        atomicAdd(&stats_i[8 + tid],  l_cp[tid]);
    }
    if (tid == 0) atomicAdd(&stats_f[16], l_zl);
}

// ---------------- offsets + loss ----------------
__global__ void offsets_loss(const float* __restrict__ stats_f, int* __restrict__ stats_i,
                             float* __restrict__ loss_out) {
    if (threadIdx.x != 0) return;
    int off = 0;
    for (int e = 0; e < 8; e++) { stats_i[24 + e] = off; off += stats_i[e]; }
    stats_i[32] = off;
    float gs = 0.f;
    for (int e = 0; e < 8; e++) gs += stats_f[8 + e];
    float var = 0.f;
    for (int e = 0; e < 8; e++) {
        float gn = stats_f[8 + e] / gs;
        float d = gn - 0.125f;
        var += d * d;
    }
    var /= 7.f;
    float cv = var / (0.015625f + 1e-10f);
    float ps = 0.f, cs = 0.f;
    for (int e = 0; e < 8; e++) { ps += stats_f[e]; cs += (float)stats_i[8 + e]; }
    float dot = 0.f;
    for (int e = 0; e < 8; e++) dot += (stats_f[e] / ps) * ((float)stats_i[8 + e] / cs);
    float sw = (1.f - dot) * 8.f;
    float zl = stats_f[16] / (float)TT;
    *loss_out = 0.01f * cv + 0.1f * sw + 0.0001f * zl;
}

// ---------------- scatter pairs ----------------
__global__ void scatter(const int* __restrict__ top_i, int* __restrict__ stats_i,
                        int* __restrict__ row_token, int* __restrict__ pair_pos) {
    __shared__ int lcnt[8], lbase[8];
    int tid = threadIdx.x;
    if (tid < 8) lcnt[tid] = 0;
    __syncthreads();
    int t = blockIdx.x * 256 + tid;
    int e0 = top_i[t * 2], e1 = top_i[t * 2 + 1];
    int p0 = atomicAdd(&lcnt[e0], 1);
    int p1 = atomicAdd(&lcnt[e1], 1);
    __syncthreads();
    if (tid < 8) lbase[tid] = atomicAdd(&stats_i[16 + tid], lcnt[tid]);
    __syncthreads();
    const int* offs = stats_i + 24;
    int idx0 = offs[e0] + lbase[e0] + p0;
    int idx1 = offs[e1] + lbase[e1] + p1;
    row_token[idx0] = t;
    row_token[idx1] = t;
    pair_pos[t * 2] = idx0;
    pair_pos[t * 2 + 1] = idx1;
}

// ---------------- grouped GEMM: C[rows, N] = A[rows, K] @ Bt[N, K]^T ----------------
// 128x128 tile, BK=64, 4 waves each computing a 64x64 quadrant via 16x16x32 bf16 MFMA.
template<int KDIM, bool GATHER, bool RELU>
__global__ __launch_bounds__(256) void gemm_tile(
    const unsigned short* __restrict__ A,
    const unsigned short* __restrict__ Bt,
    unsigned short* __restrict__ C, int ldc,
    const int* __restrict__ row_token, const int* __restrict__ stats_i) {
    const int* offs = stats_i + 24;
    int e  = blockIdx.z;
    int off = offs[e];
    int ne  = offs[e + 1] - off;
    int rt = blockIdx.x;
    if (rt * 128 >= ne) return;
    int n0 = blockIdx.y * 128;
    int NDIM = gridDim.y * 128;
    __shared__ __align__(16) unsigned short Al[128 * 64];
    __shared__ __align__(16) unsigned short Bl[128 * 64];
    __shared__ int toks[128];
    int tid = threadIdx.x;
    if (GATHER) {
        if (tid < 128) toks[tid] = row_token[min(off + rt * 128 + tid, TK - 1)];
    }
    __syncthreads();
    int lane = tid & 63, wave = tid >> 6;
    int wm = wave >> 1, wn = wave & 1;
    f32x4 acc[4][4];
#pragma unroll
    for (int m = 0; m < 4; m++)
#pragma unroll
        for (int n = 0; n < 4; n++)
#pragma unroll
            for (int i = 0; i < 4; i++) acc[m][n][i] = 0.f;
    const unsigned short* Bte = Bt + (size_t)e * NDIM * KDIM;
    for (int kb = 0; kb < KDIM / 64; ++kb) {
#pragma unroll
        for (int r = 0; r < 4; r++) {
            int glin = r * 256 + tid;
            int row = glin >> 3, sl = glin & 7, g = sl ^ (row & 7);
            const unsigned short* srcA;
            if (GATHER) {
                srcA = A + (size_t)toks[row] * KDIM + kb * 64 + g * 8;
            } else {
                int ar = min(off + rt * 128 + row, TK - 1);
                srcA = A + (size_t)ar * KDIM + kb * 64 + g * 8;
            }
            GLOAD_LDS16(srcA, Al + r * 2048 + wave * 512);
            const unsigned short* srcB = Bte + (size_t)(n0 + row) * KDIM + kb * 64 + g * 8;
            GLOAD_LDS16(srcB, Bl + r * 2048 + wave * 512);
        }
        __syncthreads();
#pragma unroll
        for (int kk = 0; kk < 2; kk++) {
            bf16x8 av[4], bv[4];
#pragma unroll
            for (int m = 0; m < 4; m++) {
                int row = wm * 64 + m * 16 + (lane & 15);
                int g = (kk * 4 + (lane >> 4)) ^ (row & 7);
                av[m] = *(const bf16x8*)(Al + row * 64 + g * 8);
            }
#pragma unroll
            for (int n = 0; n < 4; n++) {
                int row = wn * 64 + n * 16 + (lane & 15);
                int g = (kk * 4 + (lane >> 4)) ^ (row & 7);
                bv[n] = *(const bf16x8*)(Bl + row * 64 + g * 8);
            }
#pragma unroll
            for (int m = 0; m < 4; m++)
#pragma unroll
                for (int n = 0; n < 4; n++)
                    acc[m][n] = __builtin_amdgcn_mfma_f32_16x16x32_bf16(av[m], bv[n], acc[m][n], 0, 0, 0);
        }
        __syncthreads();
    }
#pragma unroll
    for (int m = 0; m < 4; m++) {
        int rr0 = rt * 128 + wm * 64 + m * 16 + (lane >> 4) * 4;
#pragma unroll
        for (int i = 0; i < 4; i++) {
            if (rr0 + i < ne) {
                size_t grow = (size_t)(off + rr0 + i);
#pragma unroll
                for (int n = 0; n < 4; n++) {
                    int col = n0 + wn * 64 + n * 16 + (lane & 15);
                    float v = acc[m][n][i];
                    if (RELU) v = fmaxf(v, 0.f);
                    C[grow * ldc + col] = f2b(v);
                }
            }
        }
    }
}

// ---------------- gated combine ----------------
__global__ void combine(const unsigned short* __restrict__ outp,
                        const int* __restrict__ pair_pos, const float* __restrict__ top_g,
                        float* __restrict__ y) {
    int t = blockIdx.x;
    int tid = threadIdx.x;
    int i0 = pair_pos[t * 2], i1 = pair_pos[t * 2 + 1];
    float g0 = top_g[t * 2], g1 = top_g[t * 2 + 1];
    int d0 = tid * 4;
    ushort4 a = *(const ushort4*)(outp + (size_t)i0 * DD + d0);
    ushort4 b = *(const ushort4*)(outp + (size_t)i1 * DD + d0);
    float4 o;
    o.x = g0 * b2f(a.x) + g1 * b2f(b.x);
    o.y = g0 * b2f(a.y) + g1 * b2f(b.y);
    o.z = g0 * b2f(a.z) + g1 * b2f(b.z);
    o.w = g0 * b2f(a.w) + g1 * b2f(b.w);
    *(float4*)(y + (size_t)t * DD + d0) = o;
}

extern "C" void kernel_launch(void* const* d_in, const int* in_sizes, int n_in,
                              void* d_out, int out_size, void* d_ws, size_t ws_size,
                              hipStream_t stream) {
    const float* x   = (const float*)d_in[0];
    const float* wg  = (const float*)d_in[1];
    const float* w1  = (const float*)d_in[2];
    const float* w2  = (const float*)d_in[3];
    const float* eps = (const float*)d_in[4];
    float* y = (float*)d_out;
    char* ws = (char*)d_ws;

    unsigned short* xb    = (unsigned short*)(ws);                 //  8 MB
    unsigned short* w1bT  = (unsigned short*)(ws + 8388608);       // 32 MB  [E][H][D]
    unsigned short* w2bT  = (unsigned short*)(ws + 41943040);      // 32 MB  [E][D][H]
    unsigned short* hbuf  = (unsigned short*)(ws + 75497472);      // 32 MB  [TK][H]
    unsigned short* outp  = (unsigned short*)(ws + 109051904);     // 16 MB  [TK][D]
    int*   top_i    = (int*)(ws + 125829120);
    float* top_g    = (float*)(ws + 125861888);
    int*   row_token= (int*)(ws + 125894656);
    int*   pair_pos = (int*)(ws + 125927424);
    float* stats_f  = (float*)(ws + 125960192);
    int*   stats_i  = (int*)(ws + 125960192 + 128);

    zero_stats<<<1, 128, 0, stream>>>((int*)(ws + 125960192));
    conv_transpose<<<dim3(32, 16, 8), 256, 0, stream>>>(w1, w1bT, 1024, 2048);
    conv_transpose<<<dim3(16, 32, 8), 256, 0, stream>>>(w2, w2bT, 2048, 1024);
    gating<<<1024, 256, 0, stream>>>(x, wg, eps, stats_f, stats_i, top_i, top_g, xb);
    offsets_loss<<<1, 64, 0, stream>>>(stats_f, stats_i, y + (size_t)TT * DD);
    scatter<<<16, 256, 0, stream>>>(top_i, stats_i, row_token, pair_pos);
    gemm_tile<1024, true,  true ><<<dim3(32, 16, 8), 256, 0, stream>>>(xb,   w1bT, hbuf, HH, row_token, stats_i);
    gemm_tile<2048, false, false><<<dim3(32, 8, 8),  256, 0, stream>>>(hbuf, w2bT, outp, DD, row_token, stats_i);
    combine<<<4096, 256, 0, stream>>>(outp, pair_pos, top_g, y);
}

// Round 3
// 267.286 us; speedup vs baseline: 2.1553x; 1.5203x over previous
//
#include <hip/hip_runtime.h>

// Problem constants
#define TT 4096      // tokens (B*L)
#define DD 1024      // model dim
#define HH 2048      // hidden dim
#define EE 8         // experts
#define TK 8192      // T*K pairs (K=2)

typedef short  bf16x8 __attribute__((ext_vector_type(8)));
typedef float  f32x4  __attribute__((ext_vector_type(4)));

__device__ __forceinline__ unsigned short f2b(float f) {
    unsigned int u = __float_as_uint(f);
    unsigned int r = (u + 0x7fffu + ((u >> 16) & 1u)) >> 16;  // RNE
    return (unsigned short)r;
}
__device__ __forceinline__ float b2f(unsigned short b) {
    return __uint_as_float(((unsigned int)b) << 16);
}

#define GLOAD_LDS16(SRC, DST) __builtin_amdgcn_global_load_lds( \
    (const __attribute__((address_space(1))) unsigned int*)(SRC), \
    (__attribute__((address_space(3))) unsigned int*)(DST), 16, 0, 0)

// ------------- weight transpose + bf16 convert: src [E][Kd][Nd] -> dst [E][Nd][Kd] -------------
__global__ void conv_transpose(const float* __restrict__ src, unsigned short* __restrict__ dst,
                               int Kd, int Nd) {
    int e  = blockIdx.z;
    int n0 = blockIdx.x * 64;
    int k0 = blockIdx.y * 64;
    const float* s = src + (size_t)e * Kd * Nd;
    unsigned short* d = dst + (size_t)e * Kd * Nd;
    __shared__ float tile[64][65];
    int c  = threadIdx.x & 63;
    int r4 = threadIdx.x >> 6;
#pragma unroll
    for (int i = 0; i < 16; i++) {
        int r = r4 + i * 4;
        tile[r][c] = s[(size_t)(k0 + r) * Nd + n0 + c];
    }
    __syncthreads();
#pragma unroll
    for (int i = 0; i < 16; i++) {
        int r = r4 + i * 4;
        d[(size_t)(n0 + r) * Kd + k0 + c] = f2b(tile[c][r]);
    }
}

// ---------------- stats zero ----------------
__global__ void zero_stats(int* p) {
    if (threadIdx.x < 128) p[threadIdx.x] = 0;
}

// ---------------- gating (one token per wave) + fused x->bf16 convert ----------------
__global__ __launch_bounds__(256) void gating(const float* __restrict__ x, const float* __restrict__ wg,
                       const float* __restrict__ eps,
                       float* __restrict__ stats_f, int* __restrict__ stats_i,
                       int* __restrict__ top_i, float* __restrict__ top_g,
                       unsigned short* __restrict__ xb) {
    __shared__ float l_psum[8], l_gsum[8], l_zl;
    __shared__ int   l_cr[8], l_cp[8];
    int tid = threadIdx.x;
    if (tid < 8) { l_psum[tid] = 0.f; l_gsum[tid] = 0.f; l_cr[tid] = 0; l_cp[tid] = 0; }
    if (tid == 0) l_zl = 0.f;
    __syncthreads();
    int wave = tid >> 6, lane = tid & 63;
    int t = blockIdx.x * 4 + wave;
    const float* xr = x + (size_t)t * DD;
    unsigned short* xbr = xb + (size_t)t * DD;
    float acc[16];
#pragma unroll
    for (int j = 0; j < 16; j++) acc[j] = 0.f;
#pragma unroll
    for (int i = 0; i < 16; i++) {
        int dd = lane + i * 64;
        float xv = xr[dd];
        xbr[dd] = f2b(xv);
        const float4* wr = (const float4*)(wg + dd * 16);
        float4 w0 = wr[0], w1 = wr[1], w2 = wr[2], w3 = wr[3];
        acc[0]  += xv * w0.x; acc[1]  += xv * w0.y; acc[2]  += xv * w0.z; acc[3]  += xv * w0.w;
        acc[4]  += xv * w1.x; acc[5]  += xv * w1.y; acc[6]  += xv * w1.z; acc[7]  += xv * w1.w;
        acc[8]  += xv * w2.x; acc[9]  += xv * w2.y; acc[10] += xv * w2.z; acc[11] += xv * w2.w;
        acc[12] += xv * w3.x; acc[13] += xv * w3.y; acc[14] += xv * w3.z; acc[15] += xv * w3.w;
    }
#pragma unroll
    for (int j = 0; j < 16; j++)
#pragma unroll
        for (int o = 32; o > 0; o >>= 1) acc[j] += __shfl_xor(acc[j], o, 64);
    if (lane == 0) {
        float lg[8], p[8];
        float mx = -1e30f;
        for (int e2 = 0; e2 < 8; e2++) {
            float raw = acc[8 + e2];
            float sp = (raw > 20.f) ? raw : log1pf(__expf(raw));
            float l = acc[e2] + eps[(size_t)t * 8 + e2] * (sp + 0.01f);
            lg[e2] = l; mx = fmaxf(mx, l);
        }
        float se = 0.f;
        for (int e2 = 0; e2 < 8; e2++) { p[e2] = __expf(lg[e2] - mx); se += p[e2]; }
        float lse = mx + logf(se);
        float inv = 1.f / se;
        for (int e2 = 0; e2 < 8; e2++) p[e2] *= inv;
        int i0 = 0;
        for (int e2 = 1; e2 < 8; e2++) if (p[e2] > p[i0]) i0 = e2;
        int i1 = (i0 == 0) ? 1 : 0;
        for (int e2 = 0; e2 < 8; e2++) if (e2 != i0 && p[e2] > p[i1]) i1 = e2;
        float g0 = p[i0], g1 = p[i1];
        top_i[t * 2] = i0; top_i[t * 2 + 1] = i1;
        top_g[t * 2] = g0; top_g[t * 2 + 1] = g1;
        for (int e2 = 0; e2 < 8; e2++) atomicAdd(&l_psum[e2], p[e2]);
        atomicAdd(&l_gsum[i0], g0); atomicAdd(&l_gsum[i1], g1);
        atomicAdd(&l_zl, lse * lse);
        atomicAdd(&l_cr[i0], 1); atomicAdd(&l_cr[i1], 1);
        if (g0 > 0.f) atomicAdd(&l_cp[i0], 1);
        if (g1 > 0.f) atomicAdd(&l_cp[i1], 1);
    }
    __syncthreads();
    if (tid < 8) {
        atomicAdd(&stats_f[tid],      l_psum[tid]);
        atomicAdd(&stats_f[8 + tid],  l_gsum[tid]);
        atomicAdd(&stats_i[tid],      l_cr[tid]);
        atomicAdd(&stats_i[8 + tid],  l_cp[tid]);
    }
    if (tid == 0) atomicAdd(&stats_f[16], l_zl);
}

// ---------------- offsets + loss ----------------
__global__ void offsets_loss(const float* __restrict__ stats_f, int* __restrict__ stats_i,
                             float* __restrict__ loss_out) {
    if (threadIdx.x != 0) return;
    int off = 0;
    for (int e = 0; e < 8; e++) { stats_i[24 + e] = off; off += stats_i[e]; }
    stats_i[32] = off;
    float gs = 0.f;
    for (int e = 0; e < 8; e++) gs += stats_f[8 + e];
    float var = 0.f;
    for (int e = 0; e < 8; e++) {
        float gn = stats_f[8 + e] / gs;
        float d = gn - 0.125f;
        var += d * d;
    }
    var /= 7.f;
    float cv = var / (0.015625f + 1e-10f);
    float ps = 0.f, cs = 0.f;
    for (int e = 0; e < 8; e++) { ps += stats_f[e]; cs += (float)stats_i[8 + e]; }
    float dot = 0.f;
    for (int e = 0; e < 8; e++) dot += (stats_f[e] / ps) * ((float)stats_i[8 + e] / cs);
    float sw = (1.f - dot) * 8.f;
    float zl = stats_f[16] / (float)TT;
    *loss_out = 0.01f * cv + 0.1f * sw + 0.0001f * zl;
}

// ---------------- scatter pairs ----------------
__global__ void scatter(const int* __restrict__ top_i, int* __restrict__ stats_i,
                        int* __restrict__ row_token, int* __restrict__ pair_pos) {
    __shared__ int lcnt[8], lbase[8];
    int tid = threadIdx.x;
    if (tid < 8) lcnt[tid] = 0;
    __syncthreads();
    int t = blockIdx.x * 256 + tid;
    int e0 = top_i[t * 2], e1 = top_i[t * 2 + 1];
    int p0 = atomicAdd(&lcnt[e0], 1);
    int p1 = atomicAdd(&lcnt[e1], 1);
    __syncthreads();
    if (tid < 8) lbase[tid] = atomicAdd(&stats_i[16 + tid], lcnt[tid]);
    __syncthreads();
    const int* offs = stats_i + 24;
    int idx0 = offs[e0] + lbase[e0] + p0;
    int idx1 = offs[e1] + lbase[e1] + p1;
    row_token[idx0] = t;
    row_token[idx1] = t;
    pair_pos[t * 2] = idx0;
    pair_pos[t * 2 + 1] = idx1;
}

// ---------------- grouped GEMM, 256xBN tile, BK=64, 2-phase double-buffered ----------------
// 8 waves (2M x 4N), each wave owns a 128 x (BN/4) output sub-tile.
// Grid MUST be (16, 8, 8): x=m-tile, y=n-tile, z=expert (pre-swizzle).
template<int BN, int KDIM, bool GATHER, bool RELU>
__global__ __launch_bounds__(512, 2) void gemm256(
    const unsigned short* __restrict__ A,
    const unsigned short* __restrict__ Bt,
    unsigned short* __restrict__ C, int ldc,
    const int* __restrict__ row_token, const int* __restrict__ stats_i) {
    constexpr int BM = 256, BK = 64;
    constexpr int NB_A = (BM * BK * 2) / (512 * 16);   // 4
    constexpr int NB_B = (BN * BK * 2) / (512 * 16);   // 4 (BN=256) or 2 (BN=128)
    constexpr int NFB  = BN / 64;                      // n-fragments per wave
    constexpr int NDIM = BN * 8;
    constexpr int NK   = KDIM / BK;

    // XCD swizzle: linear id -> (expert = lin%8 on its own XCD)
    int lin = blockIdx.x + 16 * (blockIdx.y + 8 * blockIdx.z);
    int swz = (lin & 7) * 128 + (lin >> 3);
    int rt = swz & 15;
    int n0 = ((swz >> 4) & 7) * BN;
    int e  = swz >> 7;

    const int* offs = stats_i + 24;
    int off = offs[e];
    int ne  = offs[e + 1] - off;
    if (rt * BM >= ne) return;

    __shared__ __align__(16) unsigned short Al[2][BM * BK];
    __shared__ __align__(16) unsigned short Bl[2][BN * BK];

    int tid = threadIdx.x;
    int lane = tid & 63, wave = tid >> 6;
    int wm = wave >> 2, wn = wave & 3;

    // per-thread staging source pointers (4 A rows, NB_B B rows), XOR-pre-swizzled
    const unsigned short* Asrc[NB_A];
#pragma unroll
    for (int i = 0; i < NB_A; i++) {
        int glin = i * 512 + tid;
        int row = glin >> 3, sl = glin & 7, g = sl ^ (row & 7);
        int arow;
        if (GATHER) arow = row_token[min(off + rt * BM + row, TK - 1)];
        else        arow = min(off + rt * BM + row, TK - 1);
        Asrc[i] = A + (size_t)arow * KDIM + g * 8;
    }
    const unsigned short* Bte = Bt + (size_t)e * NDIM * KDIM;
    const unsigned short* Bsrc[NB_B];
#pragma unroll
    for (int i = 0; i < NB_B; i++) {
        int glin = i * 512 + tid;
        int row = glin >> 3, sl = glin & 7, g = sl ^ (row & 7);
        Bsrc[i] = Bte + (size_t)(n0 + row) * KDIM + g * 8;
    }

    f32x4 acc[8][NFB];
#pragma unroll
    for (int m = 0; m < 8; m++)
#pragma unroll
        for (int n = 0; n < NFB; n++)
#pragma unroll
            for (int i = 0; i < 4; i++) acc[m][n][i] = 0.f;

    // prologue: stage tile 0 into buf 0
#pragma unroll
    for (int i = 0; i < NB_A; i++) GLOAD_LDS16(Asrc[i], &Al[0][i * 4096 + wave * 512]);
#pragma unroll
    for (int i = 0; i < NB_B; i++) GLOAD_LDS16(Bsrc[i], &Bl[0][i * 4096 + wave * 512]);
    asm volatile("s_waitcnt vmcnt(0)" ::: "memory");
    __builtin_amdgcn_s_barrier();

    int cur = 0;
#pragma unroll 1
    for (int kb = 0; kb < NK; ++kb) {
        // issue next tile's loads first (they fly under the MFMAs below)
        if (kb + 1 < NK) {
            int nxt = cur ^ 1;
#pragma unroll
            for (int i = 0; i < NB_A; i++)
                GLOAD_LDS16(Asrc[i] + (kb + 1) * 64, &Al[nxt][i * 4096 + wave * 512]);
#pragma unroll
            for (int i = 0; i < NB_B; i++)
                GLOAD_LDS16(Bsrc[i] + (kb + 1) * 64, &Bl[nxt][i * 4096 + wave * 512]);
        }
        // compute on current buffer
#pragma unroll
        for (int kk = 0; kk < 2; kk++) {
            bf16x8 av[8], bv[NFB];
#pragma unroll
            for (int m = 0; m < 8; m++) {
                int row = wm * 128 + m * 16 + (lane & 15);
                int g = (kk * 4 + (lane >> 4)) ^ (row & 7);
                av[m] = *(const bf16x8*)(&Al[cur][row * 64 + g * 8]);
            }
#pragma unroll
            for (int n = 0; n < NFB; n++) {
                int row = wn * (BN / 4) + n * 16 + (lane & 15);
                int g = (kk * 4 + (lane >> 4)) ^ (row & 7);
                bv[n] = *(const bf16x8*)(&Bl[cur][row * 64 + g * 8]);
            }
#pragma unroll
            for (int m = 0; m < 8; m++)
#pragma unroll
                for (int n = 0; n < NFB; n++)
                    acc[m][n] = __builtin_amdgcn_mfma_f32_16x16x32_bf16(av[m], bv[n], acc[m][n], 0, 0, 0);
        }
        // one combined drain + barrier per K-tile
        asm volatile("s_waitcnt vmcnt(0) lgkmcnt(0)" ::: "memory");
        __builtin_amdgcn_sched_barrier(0);
        __builtin_amdgcn_s_barrier();
        cur ^= 1;
    }

    // epilogue
#pragma unroll
    for (int m = 0; m < 8; m++) {
        int rr0 = rt * BM + wm * 128 + m * 16 + (lane >> 4) * 4;
#pragma unroll
        for (int i = 0; i < 4; i++) {
            if (rr0 + i < ne) {
                size_t grow = (size_t)(off + rr0 + i);
#pragma unroll
                for (int n = 0; n < NFB; n++) {
                    int col = n0 + wn * (BN / 4) + n * 16 + (lane & 15);
                    float v = acc[m][n][i];
                    if (RELU) v = fmaxf(v, 0.f);
                    C[grow * ldc + col] = f2b(v);
                }
            }
        }
    }
}

// ---------------- gated combine ----------------
__global__ void combine(const unsigned short* __restrict__ outp,
                        const int* __restrict__ pair_pos, const float* __restrict__ top_g,
                        float* __restrict__ y) {
    int t = blockIdx.x;
    int tid = threadIdx.x;
    int i0 = pair_pos[t * 2], i1 = pair_pos[t * 2 + 1];
    float g0 = top_g[t * 2], g1 = top_g[t * 2 + 1];
    int d0 = tid * 4;
    ushort4 a = *(const ushort4*)(outp + (size_t)i0 * DD + d0);
    ushort4 b = *(const ushort4*)(outp + (size_t)i1 * DD + d0);
    float4 o;
    o.x = g0 * b2f(a.x) + g1 * b2f(b.x);
    o.y = g0 * b2f(a.y) + g1 * b2f(b.y);
    o.z = g0 * b2f(a.z) + g1 * b2f(b.z);
    o.w = g0 * b2f(a.w) + g1 * b2f(b.w);
    *(float4*)(y + (size_t)t * DD + d0) = o;
}

extern "C" void kernel_launch(void* const* d_in, const int* in_sizes, int n_in,
                              void* d_out, int out_size, void* d_ws, size_t ws_size,
                              hipStream_t stream) {
    const float* x   = (const float*)d_in[0];
    const float* wg  = (const float*)d_in[1];
    const float* w1  = (const float*)d_in[2];
    const float* w2  = (const float*)d_in[3];
    const float* eps = (const float*)d_in[4];
    float* y = (float*)d_out;
    char* ws = (char*)d_ws;

    unsigned short* xb    = (unsigned short*)(ws);                 //  8 MB
    unsigned short* w1bT  = (unsigned short*)(ws + 8388608);       // 32 MB  [E][H][D]
    unsigned short* w2bT  = (unsigned short*)(ws + 41943040);      // 32 MB  [E][D][H]
    unsigned short* hbuf  = (unsigned short*)(ws + 75497472);      // 32 MB  [TK][H]
    unsigned short* outp  = (unsigned short*)(ws + 109051904);     // 16 MB  [TK][D]
    int*   top_i    = (int*)(ws + 125829120);
    float* top_g    = (float*)(ws + 125861888);
    int*   row_token= (int*)(ws + 125894656);
    int*   pair_pos = (int*)(ws + 125927424);
    float* stats_f  = (float*)(ws + 125960192);
    int*   stats_i  = (int*)(ws + 125960192 + 128);

    zero_stats<<<1, 128, 0, stream>>>((int*)(ws + 125960192));
    conv_transpose<<<dim3(32, 16, 8), 256, 0, stream>>>(w1, w1bT, 1024, 2048);
    conv_transpose<<<dim3(16, 32, 8), 256, 0, stream>>>(w2, w2bT, 2048, 1024);
    gating<<<1024, 256, 0, stream>>>(x, wg, eps, stats_f, stats_i, top_i, top_g, xb);
    offsets_loss<<<1, 64, 0, stream>>>(stats_f, stats_i, y + (size_t)TT * DD);
    scatter<<<16, 256, 0, stream>>>(top_i, stats_i, row_token, pair_pos);
    gemm256<256, 1024, true,  true ><<<dim3(16, 8, 8), 512, 0, stream>>>(xb,   w1bT, hbuf, HH, row_token, stats_i);
    gemm256<128, 2048, false, false><<<dim3(16, 8, 8), 512, 0, stream>>>(hbuf, w2bT, outp, DD, row_token, stats_i);
    combine<<<4096, 256, 0, stream>>>(outp, pair_pos, top_g, y);
}

// Round 4
// 262.038 us; speedup vs baseline: 2.1985x; 1.0200x over previous
//
#include <hip/hip_runtime.h>

// Problem constants
#define TT 4096      // tokens (B*L)
#define DD 1024      // model dim
#define HH 2048      // hidden dim
#define EE 8         // experts
#define TK 8192      // T*K pairs (K=2)

typedef short  bf16x8 __attribute__((ext_vector_type(8)));
typedef float  f32x4  __attribute__((ext_vector_type(4)));

__device__ __forceinline__ unsigned short f2b(float f) {
    unsigned int u = __float_as_uint(f);
    unsigned int r = (u + 0x7fffu + ((u >> 16) & 1u)) >> 16;  // RNE
    return (unsigned short)r;
}
__device__ __forceinline__ float b2f(unsigned short b) {
    return __uint_as_float(((unsigned int)b) << 16);
}

#define GLOAD_LDS16(SRC, DST) __builtin_amdgcn_global_load_lds( \
    (const __attribute__((address_space(1))) unsigned int*)(SRC), \
    (__attribute__((address_space(3))) unsigned int*)(DST), 16, 0, 0)

// ------------- weight transpose + bf16 convert: src [E][Kd][Nd] -> dst [E][Nd][Kd] -------------
__global__ void conv_transpose(const float* __restrict__ src, unsigned short* __restrict__ dst,
                               int Kd, int Nd) {
    int e  = blockIdx.z;
    int n0 = blockIdx.x * 64;
    int k0 = blockIdx.y * 64;
    const float* s = src + (size_t)e * Kd * Nd;
    unsigned short* d = dst + (size_t)e * Kd * Nd;
    __shared__ float tile[64][65];
    int c  = threadIdx.x & 63;
    int r4 = threadIdx.x >> 6;
#pragma unroll
    for (int i = 0; i < 16; i++) {
        int r = r4 + i * 4;
        tile[r][c] = s[(size_t)(k0 + r) * Nd + n0 + c];
    }
    __syncthreads();
#pragma unroll
    for (int i = 0; i < 16; i++) {
        int r = r4 + i * 4;
        d[(size_t)(n0 + r) * Kd + k0 + c] = f2b(tile[c][r]);
    }
}

// ---------------- stats zero ----------------
__global__ void zero_stats(int* p) {
    if (threadIdx.x < 128) p[threadIdx.x] = 0;
}

// ---------------- gating (one token per wave) + fused x->bf16 convert ----------------
__global__ __launch_bounds__(256) void gating(const float* __restrict__ x, const float* __restrict__ wg,
                       const float* __restrict__ eps,
                       float* __restrict__ stats_f, int* __restrict__ stats_i,
                       int* __restrict__ top_i, float* __restrict__ top_g,
                       unsigned short* __restrict__ xb) {
    __shared__ float l_psum[8], l_gsum[8], l_zl;
    __shared__ int   l_cr[8], l_cp[8];
    int tid = threadIdx.x;
    if (tid < 8) { l_psum[tid] = 0.f; l_gsum[tid] = 0.f; l_cr[tid] = 0; l_cp[tid] = 0; }
    if (tid == 0) l_zl = 0.f;
    __syncthreads();
    int wave = tid >> 6, lane = tid & 63;
    int t = blockIdx.x * 4 + wave;
    const float* xr = x + (size_t)t * DD;
    unsigned short* xbr = xb + (size_t)t * DD;
    float acc[16];
#pragma unroll
    for (int j = 0; j < 16; j++) acc[j] = 0.f;
#pragma unroll
    for (int i = 0; i < 16; i++) {
        int dd = lane + i * 64;
        float xv = xr[dd];
        xbr[dd] = f2b(xv);
        const float4* wr = (const float4*)(wg + dd * 16);
        float4 w0 = wr[0], w1 = wr[1], w2 = wr[2], w3 = wr[3];
        acc[0]  += xv * w0.x; acc[1]  += xv * w0.y; acc[2]  += xv * w0.z; acc[3]  += xv * w0.w;
        acc[4]  += xv * w1.x; acc[5]  += xv * w1.y; acc[6]  += xv * w1.z; acc[7]  += xv * w1.w;
        acc[8]  += xv * w2.x; acc[9]  += xv * w2.y; acc[10] += xv * w2.z; acc[11] += xv * w2.w;
        acc[12] += xv * w3.x; acc[13] += xv * w3.y; acc[14] += xv * w3.z; acc[15] += xv * w3.w;
    }
#pragma unroll
    for (int j = 0; j < 16; j++)
#pragma unroll
        for (int o = 32; o > 0; o >>= 1) acc[j] += __shfl_xor(acc[j], o, 64);
    if (lane == 0) {
        float lg[8], p[8];
        float mx = -1e30f;
        for (int e2 = 0; e2 < 8; e2++) {
            float raw = acc[8 + e2];
            float sp = (raw > 20.f) ? raw : log1pf(__expf(raw));
            float l = acc[e2] + eps[(size_t)t * 8 + e2] * (sp + 0.01f);
            lg[e2] = l; mx = fmaxf(mx, l);
        }
        float se = 0.f;
        for (int e2 = 0; e2 < 8; e2++) { p[e2] = __expf(lg[e2] - mx); se += p[e2]; }
        float lse = mx + logf(se);
        float inv = 1.f / se;
        for (int e2 = 0; e2 < 8; e2++) p[e2] *= inv;
        int i0 = 0;
        for (int e2 = 1; e2 < 8; e2++) if (p[e2] > p[i0]) i0 = e2;
        int i1 = (i0 == 0) ? 1 : 0;
        for (int e2 = 0; e2 < 8; e2++) if (e2 != i0 && p[e2] > p[i1]) i1 = e2;
        float g0 = p[i0], g1 = p[i1];
        top_i[t * 2] = i0; top_i[t * 2 + 1] = i1;
        top_g[t * 2] = g0; top_g[t * 2 + 1] = g1;
        for (int e2 = 0; e2 < 8; e2++) atomicAdd(&l_psum[e2], p[e2]);
        atomicAdd(&l_gsum[i0], g0); atomicAdd(&l_gsum[i1], g1);
        atomicAdd(&l_zl, lse * lse);
        atomicAdd(&l_cr[i0], 1); atomicAdd(&l_cr[i1], 1);
        if (g0 > 0.f) atomicAdd(&l_cp[i0], 1);
        if (g1 > 0.f) atomicAdd(&l_cp[i1], 1);
    }
    __syncthreads();
    if (tid < 8) {
        atomicAdd(&stats_f[tid],      l_psum[tid]);
        atomicAdd(&stats_f[8 + tid],  l_gsum[tid]);
        atomicAdd(&stats_i[tid],      l_cr[tid]);
        atomicAdd(&stats_i[8 + tid],  l_cp[tid]);
    }
    if (tid == 0) atomicAdd(&stats_f[16], l_zl);
}

// ---------------- offsets + loss ----------------
__global__ void offsets_loss(const float* __restrict__ stats_f, int* __restrict__ stats_i,
                             float* __restrict__ loss_out) {
    if (threadIdx.x != 0) return;
    int off = 0;
    for (int e = 0; e < 8; e++) { stats_i[24 + e] = off; off += stats_i[e]; }
    stats_i[32] = off;
    float gs = 0.f;
    for (int e = 0; e < 8; e++) gs += stats_f[8 + e];
    float var = 0.f;
    for (int e = 0; e < 8; e++) {
        float gn = stats_f[8 + e] / gs;
        float d = gn - 0.125f;
        var += d * d;
    }
    var /= 7.f;
    float cv = var / (0.015625f + 1e-10f);
    float ps = 0.f, cs = 0.f;
    for (int e = 0; e < 8; e++) { ps += stats_f[e]; cs += (float)stats_i[8 + e]; }
    float dot = 0.f;
    for (int e = 0; e < 8; e++) dot += (stats_f[e] / ps) * ((float)stats_i[8 + e] / cs);
    float sw = (1.f - dot) * 8.f;
    float zl = stats_f[16] / (float)TT;
    *loss_out = 0.01f * cv + 0.1f * sw + 0.0001f * zl;
}

// ---------------- scatter pairs ----------------
__global__ void scatter(const int* __restrict__ top_i, int* __restrict__ stats_i,
                        int* __restrict__ row_token, int* __restrict__ pair_pos) {
    __shared__ int lcnt[8], lbase[8];
    int tid = threadIdx.x;
    if (tid < 8) lcnt[tid] = 0;
    __syncthreads();
    int t = blockIdx.x * 256 + tid;
    int e0 = top_i[t * 2], e1 = top_i[t * 2 + 1];
    int p0 = atomicAdd(&lcnt[e0], 1);
    int p1 = atomicAdd(&lcnt[e1], 1);
    __syncthreads();
    if (tid < 8) lbase[tid] = atomicAdd(&stats_i[16 + tid], lcnt[tid]);
    __syncthreads();
    const int* offs = stats_i + 24;
    int idx0 = offs[e0] + lbase[e0] + p0;
    int idx1 = offs[e1] + lbase[e1] + p1;
    row_token[idx0] = t;
    row_token[idx1] = t;
    pair_pos[t * 2] = idx0;
    pair_pos[t * 2 + 1] = idx1;
}

// ---------------- grouped GEMM, 128x256 tile, BK=64, triple-buffered counted-vmcnt pipeline ----
// 8 waves (2M x 4N), each wave owns a 64x64 output sub-tile.
// Pipeline: stage(t) landed before compute(t) via vmcnt(6)+barrier; stage(t+2) issued after the
// barrier into the buffer whose data (t-1) was fully consumed before the barrier. Loads span
// barriers (never drained to 0 in the steady loop) — T3+T4.
template<int BM, int BN, int KDIM, int NDIM, bool GATHER, bool RELU>
__global__ __launch_bounds__(512, 1) void gemm_pipe(
    const unsigned short* __restrict__ A,
    const unsigned short* __restrict__ Bt,
    unsigned short* __restrict__ C,
    const int* __restrict__ row_token, const int* __restrict__ stats_i) {
    constexpr int BK   = 64;
    constexpr int NB_A = (BM * BK) / 4096;   // 2 for BM=128 (gload_lds16 instrs/thread)
    constexpr int NB_B = (BN * BK) / 4096;   // 4 for BN=256
    constexpr int NK   = KDIM / BK;
    constexpr int MT   = 4096 / BM;          // m-tiles per expert (full coverage)
    constexpr int NT   = NDIM / BN;

    int lin = blockIdx.x + MT * (blockIdx.y + NT * blockIdx.z);
    int e   = lin & 7;                        // expert pinned to XCD
    int rem = lin >> 3;
    int rt  = rem % MT;
    int n0  = (rem / MT) * BN;

    const int* offs = stats_i + 24;
    int off = offs[e];
    int ne  = offs[e + 1] - off;
    if (rt * BM >= ne) return;

    __shared__ __align__(16) unsigned short Al[3][BM * BK];
    __shared__ __align__(16) unsigned short Bl[3][BN * BK];

    int tid = threadIdx.x;
    int lane = tid & 63, wave = tid >> 6;
    int wm = wave >> 2, wn = wave & 3;

    // per-thread staging source pointers, XOR-pre-swizzled (pairs with swizzled ds_read)
    const unsigned short* Asrc[NB_A];
#pragma unroll
    for (int i = 0; i < NB_A; i++) {
        int glin = i * 512 + tid;
        int row = glin >> 3, sl = glin & 7, g = sl ^ (row & 7);
        int arow;
        if (GATHER) arow = row_token[min(off + rt * BM + row, TK - 1)];
        else        arow = min(off + rt * BM + row, TK - 1);
        Asrc[i] = A + (size_t)arow * KDIM + g * 8;
    }
    const unsigned short* Bte = Bt + (size_t)e * NDIM * KDIM;
    const unsigned short* Bsrc[NB_B];
#pragma unroll
    for (int i = 0; i < NB_B; i++) {
        int glin = i * 512 + tid;
        int row = glin >> 3, sl = glin & 7, g = sl ^ (row & 7);
        Bsrc[i] = Bte + (size_t)(n0 + row) * KDIM + g * 8;
    }

    f32x4 acc[4][4];
#pragma unroll
    for (int m = 0; m < 4; m++)
#pragma unroll
        for (int n = 0; n < 4; n++)
#pragma unroll
            for (int i = 0; i < 4; i++) acc[m][n][i] = 0.f;

#define STAGE(KT, B) do { \
    _Pragma("unroll") \
    for (int i_ = 0; i_ < NB_A; i_++) GLOAD_LDS16(Asrc[i_] + (KT) * 64, &Al[B][i_ * 4096 + wave * 512]); \
    _Pragma("unroll") \
    for (int i_ = 0; i_ < NB_B; i_++) GLOAD_LDS16(Bsrc[i_] + (KT) * 64, &Bl[B][i_ * 4096 + wave * 512]); \
} while (0)

    // prologue: two stages in flight (12 outstanding loads/wave)
    STAGE(0, 0);
    STAGE(1, 1);

    int b = 0;
#pragma unroll 1
    for (int t = 0; t < NK; ++t) {
        if (t + 1 < NK) asm volatile("s_waitcnt vmcnt(6)" ::: "memory");  // stage t landed; t+1 in flight
        else            asm volatile("s_waitcnt vmcnt(0)" ::: "memory");  // final tile
        __builtin_amdgcn_s_barrier();
        if (t + 2 < NK) {
            int b2 = b + 2; if (b2 >= 3) b2 -= 3;
            STAGE(t + 2, b2);
        }
        const unsigned short* Ab = &Al[0][0] + b * (BM * BK);
        const unsigned short* Bb = &Bl[0][0] + b * (BN * BK);
#pragma unroll
        for (int kk = 0; kk < 2; kk++) {
            bf16x8 av[4], bv[4];
#pragma unroll
            for (int m = 0; m < 4; m++) {
                int row = wm * 64 + m * 16 + (lane & 15);
                int g = (kk * 4 + (lane >> 4)) ^ (row & 7);
                av[m] = *(const bf16x8*)(Ab + row * 64 + g * 8);
            }
#pragma unroll
            for (int n = 0; n < 4; n++) {
                int row = wn * 64 + n * 16 + (lane & 15);
                int g = (kk * 4 + (lane >> 4)) ^ (row & 7);
                bv[n] = *(const bf16x8*)(Bb + row * 64 + g * 8);
            }
#pragma unroll
            for (int m = 0; m < 4; m++)
#pragma unroll
                for (int n = 0; n < 4; n++)
                    acc[m][n] = __builtin_amdgcn_mfma_f32_16x16x32_bf16(av[m], bv[n], acc[m][n], 0, 0, 0);
        }
        b = (b == 2) ? 0 : b + 1;
    }
#undef STAGE

    // epilogue
#pragma unroll
    for (int m = 0; m < 4; m++) {
        int rr0 = rt * BM + wm * 64 + m * 16 + (lane >> 4) * 4;
#pragma unroll
        for (int i = 0; i < 4; i++) {
            if (rr0 + i < ne) {
                size_t grow = (size_t)(off + rr0 + i);
#pragma unroll
                for (int n = 0; n < 4; n++) {
                    int col = n0 + wn * 64 + n * 16 + (lane & 15);
                    float v = acc[m][n][i];
                    if (RELU) v = fmaxf(v, 0.f);
                    C[grow * NDIM + col] = f2b(v);
                }
            }
        }
    }
}

// ---------------- gated combine ----------------
__global__ void combine(const unsigned short* __restrict__ outp,
                        const int* __restrict__ pair_pos, const float* __restrict__ top_g,
                        float* __restrict__ y) {
    int t = blockIdx.x;
    int tid = threadIdx.x;
    int i0 = pair_pos[t * 2], i1 = pair_pos[t * 2 + 1];
    float g0 = top_g[t * 2], g1 = top_g[t * 2 + 1];
    int d0 = tid * 4;
    ushort4 a = *(const ushort4*)(outp + (size_t)i0 * DD + d0);
    ushort4 b = *(const ushort4*)(outp + (size_t)i1 * DD + d0);
    float4 o;
    o.x = g0 * b2f(a.x) + g1 * b2f(b.x);
    o.y = g0 * b2f(a.y) + g1 * b2f(b.y);
    o.z = g0 * b2f(a.z) + g1 * b2f(b.z);
    o.w = g0 * b2f(a.w) + g1 * b2f(b.w);
    *(float4*)(y + (size_t)t * DD + d0) = o;
}

extern "C" void kernel_launch(void* const* d_in, const int* in_sizes, int n_in,
                              void* d_out, int out_size, void* d_ws, size_t ws_size,
                              hipStream_t stream) {
    const float* x   = (const float*)d_in[0];
    const float* wg  = (const float*)d_in[1];
    const float* w1  = (const float*)d_in[2];
    const float* w2  = (const float*)d_in[3];
    const float* eps = (const float*)d_in[4];
    float* y = (float*)d_out;
    char* ws = (char*)d_ws;

    unsigned short* xb    = (unsigned short*)(ws);                 //  8 MB
    unsigned short* w1bT  = (unsigned short*)(ws + 8388608);       // 32 MB  [E][H][D]
    unsigned short* w2bT  = (unsigned short*)(ws + 41943040);      // 32 MB  [E][D][H]
    unsigned short* hbuf  = (unsigned short*)(ws + 75497472);      // 32 MB  [TK][H]
    unsigned short* outp  = (unsigned short*)(ws + 109051904);     // 16 MB  [TK][D]
    int*   top_i    = (int*)(ws + 125829120);
    float* top_g    = (float*)(ws + 125861888);
    int*   row_token= (int*)(ws + 125894656);
    int*   pair_pos = (int*)(ws + 125927424);
    float* stats_f  = (float*)(ws + 125960192);
    int*   stats_i  = (int*)(ws + 125960192 + 128);

    zero_stats<<<1, 128, 0, stream>>>((int*)(ws + 125960192));
    conv_transpose<<<dim3(32, 16, 8), 256, 0, stream>>>(w1, w1bT, 1024, 2048);
    conv_transpose<<<dim3(16, 32, 8), 256, 0, stream>>>(w2, w2bT, 2048, 1024);
    gating<<<1024, 256, 0, stream>>>(x, wg, eps, stats_f, stats_i, top_i, top_g, xb);
    offsets_loss<<<1, 64, 0, stream>>>(stats_f, stats_i, y + (size_t)TT * DD);
    scatter<<<16, 256, 0, stream>>>(top_i, stats_i, row_token, pair_pos);
    gemm_pipe<128, 256, 1024, 2048, true,  true ><<<dim3(32, 8, 8), 512, 0, stream>>>(xb,   w1bT, hbuf, row_token, stats_i);
    gemm_pipe<128, 256, 2048, 1024, false, false><<<dim3(32, 4, 8), 512, 0, stream>>>(hbuf, w2bT, outp, row_token, stats_i);
    combine<<<4096, 256, 0, stream>>>(outp, pair_pos, top_g, y);
}

// Round 5
// 230.068 us; speedup vs baseline: 2.5040x; 1.1390x over previous
//
#include <hip/hip_runtime.h>

// Problem constants
#define TT 4096      // tokens (B*L)
#define DD 1024      // model dim
#define HH 2048      // hidden dim
#define EE 8         // experts
#define TK 8192      // T*K pairs (K=2)

typedef short  bf16x8 __attribute__((ext_vector_type(8)));
typedef float  f32x4  __attribute__((ext_vector_type(4)));

__device__ __forceinline__ unsigned short f2b(float f) {
    unsigned int u = __float_as_uint(f);
    unsigned int r = (u + 0x7fffu + ((u >> 16) & 1u)) >> 16;  // RNE
    return (unsigned short)r;
}
__device__ __forceinline__ float b2f(unsigned short b) {
    return __uint_as_float(((unsigned int)b) << 16);
}

#define GLOAD_LDS16(SRC, DST) __builtin_amdgcn_global_load_lds( \
    (const __attribute__((address_space(1))) unsigned int*)(SRC), \
    (__attribute__((address_space(3))) unsigned int*)(DST), 16, 0, 0)

// ------------- weight transpose + bf16 convert: src [E][Kd][Nd] -> dst [E][Nd][Kd] -------------
__global__ void conv_transpose(const float* __restrict__ src, unsigned short* __restrict__ dst,
                               int Kd, int Nd) {
    int e  = blockIdx.z;
    int n0 = blockIdx.x * 64;
    int k0 = blockIdx.y * 64;
    const float* s = src + (size_t)e * Kd * Nd;
    unsigned short* d = dst + (size_t)e * Kd * Nd;
    __shared__ float tile[64][65];
    int c  = threadIdx.x & 63;
    int r4 = threadIdx.x >> 6;
#pragma unroll
    for (int i = 0; i < 16; i++) {
        int r = r4 + i * 4;
        tile[r][c] = s[(size_t)(k0 + r) * Nd + n0 + c];
    }
    __syncthreads();
#pragma unroll
    for (int i = 0; i < 16; i++) {
        int r = r4 + i * 4;
        d[(size_t)(n0 + r) * Kd + k0 + c] = f2b(tile[c][r]);
    }
}

// ---------------- stats zero ----------------
__global__ void zero_stats(int* p) {
    if (threadIdx.x < 128) p[threadIdx.x] = 0;
}

// ---------------- gating (one token per wave) + fused x->bf16 convert ----------------
__global__ __launch_bounds__(256) void gating(const float* __restrict__ x, const float* __restrict__ wg,
                       const float* __restrict__ eps,
                       float* __restrict__ stats_f, int* __restrict__ stats_i,
                       int* __restrict__ top_i, float* __restrict__ top_g,
                       unsigned short* __restrict__ xb) {
    __shared__ float l_psum[8], l_gsum[8], l_zl;
    __shared__ int   l_cr[8], l_cp[8];
    int tid = threadIdx.x;
    if (tid < 8) { l_psum[tid] = 0.f; l_gsum[tid] = 0.f; l_cr[tid] = 0; l_cp[tid] = 0; }
    if (tid == 0) l_zl = 0.f;
    __syncthreads();
    int wave = tid >> 6, lane = tid & 63;
    int t = blockIdx.x * 4 + wave;
    const float* xr = x + (size_t)t * DD;
    unsigned short* xbr = xb + (size_t)t * DD;
    float acc[16];
#pragma unroll
    for (int j = 0; j < 16; j++) acc[j] = 0.f;
#pragma unroll
    for (int i = 0; i < 16; i++) {
        int dd = lane + i * 64;
        float xv = xr[dd];
        xbr[dd] = f2b(xv);
        const float4* wr = (const float4*)(wg + dd * 16);
        float4 w0 = wr[0], w1 = wr[1], w2 = wr[2], w3 = wr[3];
        acc[0]  += xv * w0.x; acc[1]  += xv * w0.y; acc[2]  += xv * w0.z; acc[3]  += xv * w0.w;
        acc[4]  += xv * w1.x; acc[5]  += xv * w1.y; acc[6]  += xv * w1.z; acc[7]  += xv * w1.w;
        acc[8]  += xv * w2.x; acc[9]  += xv * w2.y; acc[10] += xv * w2.z; acc[11] += xv * w2.w;
        acc[12] += xv * w3.x; acc[13] += xv * w3.y; acc[14] += xv * w3.z; acc[15] += xv * w3.w;
    }
#pragma unroll
    for (int j = 0; j < 16; j++)
#pragma unroll
        for (int o = 32; o > 0; o >>= 1) acc[j] += __shfl_xor(acc[j], o, 64);
    if (lane == 0) {
        float lg[8], p[8];
        float mx = -1e30f;
        for (int e2 = 0; e2 < 8; e2++) {
            float raw = acc[8 + e2];
            float sp = (raw > 20.f) ? raw : log1pf(__expf(raw));
            float l = acc[e2] + eps[(size_t)t * 8 + e2] * (sp + 0.01f);
            lg[e2] = l; mx = fmaxf(mx, l);
        }
        float se = 0.f;
        for (int e2 = 0; e2 < 8; e2++) { p[e2] = __expf(lg[e2] - mx); se += p[e2]; }
        float lse = mx + logf(se);
        float inv = 1.f / se;
        for (int e2 = 0; e2 < 8; e2++) p[e2] *= inv;
        int i0 = 0;
        for (int e2 = 1; e2 < 8; e2++) if (p[e2] > p[i0]) i0 = e2;
        int i1 = (i0 == 0) ? 1 : 0;
        for (int e2 = 0; e2 < 8; e2++) if (e2 != i0 && p[e2] > p[i1]) i1 = e2;
        float g0 = p[i0], g1 = p[i1];
        top_i[t * 2] = i0; top_i[t * 2 + 1] = i1;
        top_g[t * 2] = g0; top_g[t * 2 + 1] = g1;
        for (int e2 = 0; e2 < 8; e2++) atomicAdd(&l_psum[e2], p[e2]);
        atomicAdd(&l_gsum[i0], g0); atomicAdd(&l_gsum[i1], g1);
        atomicAdd(&l_zl, lse * lse);
        atomicAdd(&l_cr[i0], 1); atomicAdd(&l_cr[i1], 1);
        if (g0 > 0.f) atomicAdd(&l_cp[i0], 1);
        if (g1 > 0.f) atomicAdd(&l_cp[i1], 1);
    }
    __syncthreads();
    if (tid < 8) {
        atomicAdd(&stats_f[tid],      l_psum[tid]);
        atomicAdd(&stats_f[8 + tid],  l_gsum[tid]);
        atomicAdd(&stats_i[tid],      l_cr[tid]);
        atomicAdd(&stats_i[8 + tid],  l_cp[tid]);
    }
    if (tid == 0) atomicAdd(&stats_f[16], l_zl);
}

// ---------------- offsets + loss ----------------
__global__ void offsets_loss(const float* __restrict__ stats_f, int* __restrict__ stats_i,
                             float* __restrict__ loss_out) {
    if (threadIdx.x != 0) return;
    int off = 0;
    for (int e = 0; e < 8; e++) { stats_i[24 + e] = off; off += stats_i[e]; }
    stats_i[32] = off;
    float gs = 0.f;
    for (int e = 0; e < 8; e++) gs += stats_f[8 + e];
    float var = 0.f;
    for (int e = 0; e < 8; e++) {
        float gn = stats_f[8 + e] / gs;
        float d = gn - 0.125f;
        var += d * d;
    }
    var /= 7.f;
    float cv = var / (0.015625f + 1e-10f);
    float ps = 0.f, cs = 0.f;
    for (int e = 0; e < 8; e++) { ps += stats_f[e]; cs += (float)stats_i[8 + e]; }
    float dot = 0.f;
    for (int e = 0; e < 8; e++) dot += (stats_f[e] / ps) * ((float)stats_i[8 + e] / cs);
    float sw = (1.f - dot) * 8.f;
    float zl = stats_f[16] / (float)TT;
    *loss_out = 0.01f * cv + 0.1f * sw + 0.0001f * zl;
}

// ---------------- scatter pairs ----------------
__global__ void scatter(const int* __restrict__ top_i, int* __restrict__ stats_i,
                        int* __restrict__ row_token, int* __restrict__ pair_pos) {
    __shared__ int lcnt[8], lbase[8];
    int tid = threadIdx.x;
    if (tid < 8) lcnt[tid] = 0;
    __syncthreads();
    int t = blockIdx.x * 256 + tid;
    int e0 = top_i[t * 2], e1 = top_i[t * 2 + 1];
    int p0 = atomicAdd(&lcnt[e0], 1);
    int p1 = atomicAdd(&lcnt[e1], 1);
    __syncthreads();
    if (tid < 8) lbase[tid] = atomicAdd(&stats_i[16 + tid], lcnt[tid]);
    __syncthreads();
    const int* offs = stats_i + 24;
    int idx0 = offs[e0] + lbase[e0] + p0;
    int idx1 = offs[e1] + lbase[e1] + p1;
    row_token[idx0] = t;
    row_token[idx1] = t;
    pair_pos[t * 2] = idx0;
    pair_pos[t * 2 + 1] = idx1;
}

// ============ grouped GEMM, 256x256 tile, BK=64, 8-phase schedule (T3+T4+T5) ============
// 8 waves (2M x 4N), per-wave output 128x64 (8x4 fragments). 2 K-tiles per iteration,
// 4 phases each (one quadrant = 2 m-frags x 4 n-frags x K=64 -> 16 MFMA).
// Chunk ring: each K-tile = 8 chunks (A0-3,B0-3; 64 rows x 64 K each, 2 gload_lds/thread per
// chunk-pair). Stage 2 chunks/phase; vmcnt(6) at phases 4/8 only (3 chunk-pairs in flight).
// Ledger (iter i, u=2i in slot0, v=2i+1 in slot1):
//  ph0: stage v:{A1,A3}      ph1: u+2:{B0,B1}  ph2: u+2:{B2,B3}  ph3: u+2:{A0,A2} +vmcnt(6)
//  ph4: u+2:{A1,A3}          ph5: v+2:{B0,B1}  ph6: v+2:{B2,B3}  ph7: v+2:{A0,A2} +vmcnt(6)
// Free-before-write and landed-before-read both guaranteed by the phase barriers.
template<int KTOT, int KSPLITS, int NTILES, int MT, bool GATHER, bool RELU>
__global__ __launch_bounds__(512, 1) void gemm8p(
    const unsigned short* __restrict__ A,
    const unsigned short* __restrict__ Bt,
    unsigned short* __restrict__ C, long long split_stride,
    const int* __restrict__ row_token, const int* __restrict__ stats_i) {
    constexpr int KD   = KTOT / KSPLITS;   // K handled per block
    constexpr int NK   = KD / 64;          // K-tiles
    constexpr int NI   = NK / 2;           // iterations (2 K-tiles each)
    constexpr int NDIM = NTILES * 256;
    static_assert(NTILES * KSPLITS == 8, "grid q must be 8");
    static_assert(NI >= 2, "need >=4 K-tiles");

    int lin = blockIdx.x + MT * (blockIdx.y + 8 * blockIdx.z);
    int e   = lin & 7;                     // expert pinned to XCD
    int rem = lin >> 3;
    int rt  = rem % MT;
    int q4  = rem / MT;                    // 0..7
    int n0  = (q4 % NTILES) * 256;
    int split = q4 / NTILES;

    const int* offs = stats_i + 24;
    int off = offs[e];
    int ne  = offs[e + 1] - off;
    if (rt * 256 >= ne) return;

    __shared__ __align__(16) unsigned short Al[2][256 * 64];
    __shared__ __align__(16) unsigned short Bl[2][256 * 64];

    int tid = threadIdx.x;
    int lane = tid & 63, wave = tid >> 6;
    int wm = wave >> 2, wn = wave & 3;

    // staging source pointers (XOR-pre-swizzled; pairs with swizzled ds_read)
    const unsigned short* Asrc[4];
#pragma unroll
    for (int i = 0; i < 4; i++) {
        int glin = i * 512 + tid;
        int row = glin >> 3, sl = glin & 7, g = sl ^ (row & 7);
        int arow;
        if (GATHER) arow = row_token[min(off + rt * 256 + row, TK - 1)];
        else        arow = min(off + rt * 256 + row, TK - 1);
        Asrc[i] = A + (size_t)arow * KTOT + split * KD + g * 8;
    }
    const unsigned short* Bte = Bt + (size_t)e * NDIM * KTOT;
    const unsigned short* Bsrc[4];
#pragma unroll
    for (int i = 0; i < 4; i++) {
        int glin = i * 512 + tid;
        int row = glin >> 3, sl = glin & 7, g = sl ^ (row & 7);
        Bsrc[i] = Bte + (size_t)(n0 + row) * KTOT + split * KD + g * 8;
    }

    f32x4 acc[8][4];
#pragma unroll
    for (int m = 0; m < 8; m++)
#pragma unroll
        for (int n = 0; n < 4; n++)
#pragma unroll
            for (int i = 0; i < 4; i++) acc[m][n][i] = 0.f;

    bf16x8 bv[2][4], av[2][2];

#define STG_A(SLOT, KT, CC) GLOAD_LDS16(Asrc[CC] + (KT) * 64, &Al[SLOT][(CC) * 4096 + wave * 512])
#define STG_B(SLOT, KT, CC) GLOAD_LDS16(Bsrc[CC] + (KT) * 64, &Bl[SLOT][(CC) * 4096 + wave * 512])

#define LOAD_B(SLOT) do { \
    _Pragma("unroll") for (int kk2 = 0; kk2 < 2; kk2++) \
    _Pragma("unroll") for (int n = 0; n < 4; n++) { \
        int row = wn * 64 + n * 16 + (lane & 15); \
        int g = (kk2 * 4 + (lane >> 4)) ^ (row & 7); \
        bv[kk2][n] = *(const bf16x8*)(&Bl[SLOT][row * 64 + g * 8]); \
    } } while (0)

#define LOAD_AQ(SLOT, QQ) do { \
    _Pragma("unroll") for (int kk2 = 0; kk2 < 2; kk2++) \
    _Pragma("unroll") for (int mi = 0; mi < 2; mi++) { \
        int row = wm * 128 + (QQ) * 32 + mi * 16 + (lane & 15); \
        int g = (kk2 * 4 + (lane >> 4)) ^ (row & 7); \
        av[kk2][mi] = *(const bf16x8*)(&Al[SLOT][row * 64 + g * 8]); \
    } } while (0)

#define MFMA_Q(QQ) do { \
    _Pragma("unroll") for (int kk2 = 0; kk2 < 2; kk2++) \
    _Pragma("unroll") for (int mi = 0; mi < 2; mi++) \
    _Pragma("unroll") for (int n = 0; n < 4; n++) \
        acc[(QQ) * 2 + mi][n] = __builtin_amdgcn_mfma_f32_16x16x32_bf16(av[kk2][mi], bv[kk2][n], acc[(QQ) * 2 + mi][n], 0, 0, 0); \
    } while (0)

#define PHASE(SLOT, QQ, STAGE_STMT, WAIT_STMT) do { \
    if ((QQ) == 0) LOAD_B(SLOT); \
    LOAD_AQ(SLOT, QQ); \
    STAGE_STMT; \
    __builtin_amdgcn_s_barrier(); \
    asm volatile("s_waitcnt lgkmcnt(0)" ::: "memory"); \
    __builtin_amdgcn_s_setprio(1); \
    MFMA_Q(QQ); \
    __builtin_amdgcn_s_setprio(0); \
    WAIT_STMT; \
    __builtin_amdgcn_s_barrier(); \
    } while (0)

    // prologue: K0 fully -> slot0; K1 all but {A1,A3} -> slot1 (14 loads; wait oldest 8)
#pragma unroll
    for (int c = 0; c < 4; c++) STG_B(0, 0, c);
#pragma unroll
    for (int c = 0; c < 4; c++) STG_A(0, 0, c);
#pragma unroll
    for (int c = 0; c < 4; c++) STG_B(1, 1, c);
    STG_A(1, 1, 0); STG_A(1, 1, 2);
    asm volatile("s_waitcnt vmcnt(6)" ::: "memory");
    __builtin_amdgcn_s_barrier();

#pragma unroll 1
    for (int it = 0; it < NI; ++it) {
        int u = 2 * it, v = u + 1;
        bool ns = (it + 1 < NI);
        PHASE(0, 0, { STG_A(1, v, 1); STG_A(1, v, 3); }, {});
        PHASE(0, 1, { if (ns) { STG_B(0, u + 2, 0); STG_B(0, u + 2, 1); } }, {});
        PHASE(0, 2, { if (ns) { STG_B(0, u + 2, 2); STG_B(0, u + 2, 3); } }, {});
        PHASE(0, 3, { if (ns) { STG_A(0, u + 2, 0); STG_A(0, u + 2, 2); } },
                    { if (ns) asm volatile("s_waitcnt vmcnt(6)" ::: "memory");
                      else    asm volatile("s_waitcnt vmcnt(0)" ::: "memory"); });
        PHASE(1, 0, { if (ns) { STG_A(0, u + 2, 1); STG_A(0, u + 2, 3); } }, {});
        PHASE(1, 1, { if (ns) { STG_B(1, v + 2, 0); STG_B(1, v + 2, 1); } }, {});
        PHASE(1, 2, { if (ns) { STG_B(1, v + 2, 2); STG_B(1, v + 2, 3); } }, {});
        PHASE(1, 3, { if (ns) { STG_A(1, v + 2, 0); STG_A(1, v + 2, 2); } },
                    { if (ns) asm volatile("s_waitcnt vmcnt(6)" ::: "memory"); });
    }
#undef PHASE
#undef MFMA_Q
#undef LOAD_AQ
#undef LOAD_B
#undef STG_A
#undef STG_B

    // epilogue
    unsigned short* Cb = C + (ptrdiff_t)split * split_stride;
#pragma unroll
    for (int m = 0; m < 8; m++) {
        int rr0 = rt * 256 + wm * 128 + m * 16 + (lane >> 4) * 4;
#pragma unroll
        for (int i = 0; i < 4; i++) {
            if (rr0 + i < ne) {
                size_t grow = (size_t)(off + rr0 + i);
#pragma unroll
                for (int n = 0; n < 4; n++) {
                    int col = n0 + wn * 64 + n * 16 + (lane & 15);
                    float vvv = acc[m][n][i];
                    if (RELU) vvv = fmaxf(vvv, 0.f);
                    Cb[grow * NDIM + col] = f2b(vvv);
                }
            }
        }
    }
}

// ---------------- gated combine (sums the two GEMM2 K-splits) ----------------
__global__ void combine(const unsigned short* __restrict__ o0,
                        const unsigned short* __restrict__ o1,
                        const int* __restrict__ pair_pos, const float* __restrict__ top_g,
                        float* __restrict__ y) {
    int t = blockIdx.x;
    int tid = threadIdx.x;
    int i0 = pair_pos[t * 2], i1 = pair_pos[t * 2 + 1];
    float g0 = top_g[t * 2], g1 = top_g[t * 2 + 1];
    int d0 = tid * 4;
    ushort4 a0 = *(const ushort4*)(o0 + (size_t)i0 * DD + d0);
    ushort4 a1 = *(const ushort4*)(o1 + (size_t)i0 * DD + d0);
    ushort4 b0 = *(const ushort4*)(o0 + (size_t)i1 * DD + d0);
    ushort4 b1 = *(const ushort4*)(o1 + (size_t)i1 * DD + d0);
    float4 o;
    o.x = g0 * (b2f(a0.x) + b2f(a1.x)) + g1 * (b2f(b0.x) + b2f(b1.x));
    o.y = g0 * (b2f(a0.y) + b2f(a1.y)) + g1 * (b2f(b0.y) + b2f(b1.y));
    o.z = g0 * (b2f(a0.z) + b2f(a1.z)) + g1 * (b2f(b0.z) + b2f(b1.z));
    o.w = g0 * (b2f(a0.w) + b2f(a1.w)) + g1 * (b2f(b0.w) + b2f(b1.w));
    *(float4*)(y + (size_t)t * DD + d0) = o;
}

extern "C" void kernel_launch(void* const* d_in, const int* in_sizes, int n_in,
                              void* d_out, int out_size, void* d_ws, size_t ws_size,
                              hipStream_t stream) {
    const float* x   = (const float*)d_in[0];
    const float* wg  = (const float*)d_in[1];
    const float* w1  = (const float*)d_in[2];
    const float* w2  = (const float*)d_in[3];
    const float* eps = (const float*)d_in[4];
    float* y = (float*)d_out;
    char* ws = (char*)d_ws;

    unsigned short* xb    = (unsigned short*)(ws);                 //  8 MB
    unsigned short* w1bT  = (unsigned short*)(ws + 8388608);       // 32 MB  [E][H][D]
    unsigned short* w2bT  = (unsigned short*)(ws + 41943040);      // 32 MB  [E][D][H]
    unsigned short* hbuf  = (unsigned short*)(ws + 75497472);      // 32 MB  [TK][H]
    unsigned short* outp0 = (unsigned short*)(ws + 109051904);     // 16 MB  [TK][D] split 0
    unsigned short* outp1 = (unsigned short*)(ws + 8388608);       // 16 MB  split 1 (reuses w1bT, dead after GEMM1)
    int*   top_i    = (int*)(ws + 125829120);
    float* top_g    = (float*)(ws + 125861888);
    int*   row_token= (int*)(ws + 125894656);
    int*   pair_pos = (int*)(ws + 125927424);
    float* stats_f  = (float*)(ws + 125960192);
    int*   stats_i  = (int*)(ws + 125960192 + 128);

    zero_stats<<<1, 128, 0, stream>>>((int*)(ws + 125960192));
    conv_transpose<<<dim3(32, 16, 8), 256, 0, stream>>>(w1, w1bT, 1024, 2048);
    conv_transpose<<<dim3(16, 32, 8), 256, 0, stream>>>(w2, w2bT, 2048, 1024);
    gating<<<1024, 256, 0, stream>>>(x, wg, eps, stats_f, stats_i, top_i, top_g, xb);
    offsets_loss<<<1, 64, 0, stream>>>(stats_f, stats_i, y + (size_t)TT * DD);
    scatter<<<16, 256, 0, stream>>>(top_i, stats_i, row_token, pair_pos);
    // GEMM1: [pairs,1024] x [2048,1024]^T -> hbuf [pairs,2048], relu, gathered A
    gemm8p<1024, 1, 8, 6, true,  true ><<<dim3(6, 8, 8), 512, 0, stream>>>(
        xb, w1bT, hbuf, 0, row_token, stats_i);
    // GEMM2: [pairs,2048] x [1024,2048]^T -> outp [pairs,1024], split-K=2
    gemm8p<2048, 2, 4, 6, false, false><<<dim3(6, 8, 8), 512, 0, stream>>>(
        hbuf, w2bT, outp0, (long long)(outp1 - outp0), row_token, stats_i);
    combine<<<4096, 256, 0, stream>>>(outp0, outp1, pair_pos, top_g, y);
}